// Round 1
// baseline (223.101 us; speedup 1.0000x reference)
//
#include <hip/hip_runtime.h>

// db2 coefficients (standard Daubechies-2, matches reference construction)
constexpr float h0 = 0.48296291314469025f;  // (1+√3)/(4√2)
constexpr float h1 = 0.83651630373746900f;  // (3+√3)/(4√2)
constexpr float h2 = 0.22414386804185735f;  // (3-√3)/(4√2)
constexpr float h3 = -0.12940952255092145f; // (1-√3)/(4√2)

// lpf = [h3,h2,h1,h0]; hpf = [-h0,h1,-h2,h3]
// For output row r = 2m+er, taps hit xp rows m+3 (orig row m) and m+4
// (orig row min(m+1,511)). er=0 -> weights (f[1], f[3]); er=1 -> (f[0], f[2]).
//   lpf: er=0 -> (h2, h0); er=1 -> (h3, h1)
//   hpf: er=0 -> (h1, h3); er=1 -> (-h0, -h2)
// Channels: c0,c1 = (lpf_h, lpf_w) [LH replicates the source bug]; c2 =
// (lpf_h, hpf_w); c3 = (hpf_h, hpf_w). c0+c1 fused; c2+c3 share hpf_w.

__global__ __launch_bounds__(256) void idwt_kernel(const float4* __restrict__ x,
                                                   float2* __restrict__ out) {
    const int idx = blockIdx.x * blockDim.x + threadIdx.x;
    const int n = idx & 511;
    const int t = idx >> 9;
    const int m = t & 511;
    const int b = t >> 9;

    const int mB = (m < 511) ? m + 1 : 511;
    const int nB = (n < 511) ? n + 1 : 511;

    const int rowA = (b << 9) + m;
    const int rowB = (b << 9) + mB;

    const float4 p00 = x[(size_t)rowA * 512 + n];
    const float4 p01 = x[(size_t)rowA * 512 + nB];
    const float4 p10 = x[(size_t)rowB * 512 + n];
    const float4 p11 = x[(size_t)rowB * 512 + nB];

    // fused LL+LH channel (identical filters)
    const float L00 = p00.x + p00.y, L01 = p01.x + p01.y;
    const float L10 = p10.x + p10.y, L11 = p11.x + p11.y;

    // vertical combines, lpf rows (L and c2):
    const float Lv0A = h2 * L00 + h0 * L10;     // er=0, col A
    const float Lv0B = h2 * L01 + h0 * L11;
    const float Lv1A = h3 * L00 + h1 * L10;     // er=1
    const float Lv1B = h3 * L01 + h1 * L11;

    const float C2v0A = h2 * p00.z + h0 * p10.z;
    const float C2v0B = h2 * p01.z + h0 * p11.z;
    const float C2v1A = h3 * p00.z + h1 * p10.z;
    const float C2v1B = h3 * p01.z + h1 * p11.z;

    // vertical combines, hpf rows (c3):
    const float C3v0A = h1 * p00.w + h3 * p10.w;
    const float C3v0B = h1 * p01.w + h3 * p11.w;
    const float C3v1A = -h0 * p00.w - h2 * p10.w;
    const float C3v1B = -h0 * p01.w - h2 * p11.w;

    // c2 and c3 share the horizontal hpf — sum their vertical results
    const float Hv0A = C2v0A + C3v0A, Hv0B = C2v0B + C3v0B;
    const float Hv1A = C2v1A + C3v1A, Hv1B = C2v1B + C3v1B;

    // horizontal: lpf: ec=0 (h2,h0), ec=1 (h3,h1); hpf: ec=0 (h1,h3), ec=1 (-h0,-h2)
    const float o00 = h2 * Lv0A + h0 * Lv0B + h1 * Hv0A + h3 * Hv0B;
    const float o01 = h3 * Lv0A + h1 * Lv0B - h0 * Hv0A - h2 * Hv0B;
    const float o10 = h2 * Lv1A + h0 * Lv1B + h1 * Hv1A + h3 * Hv1B;
    const float o11 = h3 * Lv1A + h1 * Lv1B - h0 * Hv1A - h2 * Hv1B;

    // out is [B, 1024, 1024] fp32, viewed as float2 rows of 512
    const size_t o0 = ((size_t)(b << 10) + (m << 1)) * 512 + n;
    out[o0]       = make_float2(o00, o01);
    out[o0 + 512] = make_float2(o10, o11);
}

extern "C" void kernel_launch(void* const* d_in, const int* in_sizes, int n_in,
                              void* d_out, int out_size, void* d_ws, size_t ws_size,
                              hipStream_t stream) {
    const float4* x = (const float4*)d_in[0];
    float2* out = (float2*)d_out;
    const int total = 32 * 512 * 512;           // one thread per 2x2 output block
    idwt_kernel<<<total / 256, 256, 0, stream>>>(x, out);
}

// Round 2
// 221.951 us; speedup vs baseline: 1.0052x; 1.0052x over previous
//
#include <hip/hip_runtime.h>

// db2 coefficients (standard Daubechies-2, matches reference construction)
constexpr float h0 = 0.48296291314469025f;  // (1+√3)/(4√2)
constexpr float h1 = 0.83651630373746900f;  // (3+√3)/(4√2)
constexpr float h2 = 0.22414386804185735f;  // (3-√3)/(4√2)
constexpr float h3 = -0.12940952255092145f; // (1-√3)/(4√2)

// lpf = [h3,h2,h1,h0]; hpf = [-h0,h1,-h2,h3]
// Output row r = 2m+er taps orig rows m, min(m+1,511).
//   lpf vertical: er=0 -> (h2, h0); er=1 -> (h3, h1)
//   hpf vertical: er=0 -> (h1, h3); er=1 -> (-h0, -h2)
// Channels: c0,c1 = (lpf,lpf) [LH replicates source bug -> pre-summed];
// c2 = (lpf_h, hpf_w); c3 = (hpf_h, hpf_w); c2,c3 share horizontal hpf.
//
// One thread handles 2 input columns (n0, n0+1) -> 2x4 output block,
// stored as two float4 (16 B/lane coalesced). Loads 6 float4 (2 rows x 3 cols).

__global__ __launch_bounds__(256) void idwt_kernel(const float4* __restrict__ x,
                                                   float4* __restrict__ out) {
    const int idx = blockIdx.x * blockDim.x + threadIdx.x;
    const int np = idx & 255;        // column-pair index, 256 per row
    const int t = idx >> 8;
    const int m = t & 511;
    const int b = t >> 9;

    const int n0 = np << 1;
    const int n2 = (n0 + 2 < 512) ? n0 + 2 : 511;   // clamp only at np==255
    const int mB = (m < 511) ? m + 1 : 511;

    const size_t rowA = (size_t)((b << 9) + m) * 512;
    const size_t rowB = (size_t)((b << 9) + mB) * 512;

    const float4 pA0 = x[rowA + n0], pA1 = x[rowA + n0 + 1], pA2 = x[rowA + n2];
    const float4 pB0 = x[rowB + n0], pB1 = x[rowB + n0 + 1], pB2 = x[rowB + n2];

    float Lv0[3], Lv1[3], Hv0[3], Hv1[3];
    {
        const float4 pa[3] = {pA0, pA1, pA2};
        const float4 pb[3] = {pB0, pB1, pB2};
#pragma unroll
        for (int j = 0; j < 3; ++j) {
            const float LA = pa[j].x + pa[j].y;
            const float LB = pb[j].x + pb[j].y;
            Lv0[j] = h2 * LA + h0 * LB;
            Lv1[j] = h3 * LA + h1 * LB;
            Hv0[j] = (h2 * pa[j].z + h0 * pb[j].z) + (h1 * pa[j].w + h3 * pb[j].w);
            Hv1[j] = (h3 * pa[j].z + h1 * pb[j].z) + (-h0 * pa[j].w - h2 * pb[j].w);
        }
    }

    // horizontal: lpf ec=0 (h2,h0), ec=1 (h3,h1); hpf ec=0 (h1,h3), ec=1 (-h0,-h2)
    float4 r0, r1;
    r0.x = h2 * Lv0[0] + h0 * Lv0[1] + h1 * Hv0[0] + h3 * Hv0[1];
    r0.y = h3 * Lv0[0] + h1 * Lv0[1] - h0 * Hv0[0] - h2 * Hv0[1];
    r0.z = h2 * Lv0[1] + h0 * Lv0[2] + h1 * Hv0[1] + h3 * Hv0[2];
    r0.w = h3 * Lv0[1] + h1 * Lv0[2] - h0 * Hv0[1] - h2 * Hv0[2];
    r1.x = h2 * Lv1[0] + h0 * Lv1[1] + h1 * Hv1[0] + h3 * Hv1[1];
    r1.y = h3 * Lv1[0] + h1 * Lv1[1] - h0 * Hv1[0] - h2 * Hv1[1];
    r1.z = h2 * Lv1[1] + h0 * Lv1[2] + h1 * Hv1[1] + h3 * Hv1[2];
    r1.w = h3 * Lv1[1] + h1 * Lv1[2] - h0 * Hv1[1] - h2 * Hv1[2];

    // out: [B, 1024, 1024] fp32 = rows of 256 float4; this thread owns
    // rows 2m, 2m+1, float4-col np.
    const size_t o0 = (size_t)((b << 10) + (m << 1)) * 256 + np;
    out[o0]       = r0;
    out[o0 + 256] = r1;
}

extern "C" void kernel_launch(void* const* d_in, const int* in_sizes, int n_in,
                              void* d_out, int out_size, void* d_ws, size_t ws_size,
                              hipStream_t stream) {
    const float4* x = (const float4*)d_in[0];
    float4* out = (float4*)d_out;
    const int total = 32 * 512 * 256;   // one thread per (b, m, column-pair)
    idwt_kernel<<<total / 256, 256, 0, stream>>>(x, out);
}